// Round 7
// baseline (53.438 us; speedup 1.0000x reference)
//
#include <hip/hip_runtime.h>
#include <hip/hip_bf16.h>

#define K1 784
#define N1 100
#define KT 25    // k-tiles of 32 (K padded to 800; pad rows zero in packed W)
#define NTT 7    // live n-tiles of 16 (N=100 padded to 112)
#define NTP 8    // stored n-tiles per kt (padded to 8 for 2x global_load_lds)

typedef __attribute__((ext_vector_type(8))) short bf16x8;
typedef __attribute__((ext_vector_type(4))) float f32x4;

__device__ __forceinline__ ushort f2bf(float f) {
    union { float f; unsigned u; } v; v.f = f;
    unsigned u = v.u;
    return (ushort)((u + 0x7FFFu + ((u >> 16) & 1u)) >> 16);   // RNE
}

// 8x f32 -> 8x bf16 (RNE) via 4 packed converts
__device__ __forceinline__ bf16x8 pack_bf16x8(float4 a, float4 b) {
    union { unsigned u[4]; bf16x8 v; } r;
    asm("v_cvt_pk_bf16_f32 %0, %1, %2" : "=v"(r.u[0]) : "v"(a.x), "v"(a.y));
    asm("v_cvt_pk_bf16_f32 %0, %1, %2" : "=v"(r.u[1]) : "v"(a.z), "v"(a.w));
    asm("v_cvt_pk_bf16_f32 %0, %1, %2" : "=v"(r.u[2]) : "v"(b.x), "v"(b.y));
    asm("v_cvt_pk_bf16_f32 %0, %1, %2" : "=v"(r.u[3]) : "v"(b.z), "v"(b.w));
    return r.v;
}

// async 16B global -> LDS (direct, no VGPR round-trip)
__device__ __forceinline__ void gload_lds16(const void* g, void* l) {
    __builtin_amdgcn_global_load_lds(
        (const __attribute__((address_space(1))) void*)g,
        (__attribute__((address_space(3))) void*)l, 16, 0, 0);
}

// ---------------------------------------------------------------------------
// Kernel 1: fold conv into w1 -> W_eff[k][n] (bf16 RNE), stored in MFMA
// B-fragment order: wp[(kt*8+nt)*512 + lane*8 + j] with
//   k = kt*32 + (lane>>4)*8 + j, n = nt*16 + (lane&15).
// nt=7 / k>=784 / n>=100 are zero pad. Total 25*8*512*2B = 204,800 B.
// ---------------------------------------------------------------------------
__global__ void build_wp(const float* __restrict__ w1,
                         const float* __restrict__ conv_w,
                         ushort* __restrict__ wp) {
    int idx = blockIdx.x * blockDim.x + threadIdx.x;
    if (idx >= KT * NTP * 512) return;
    int j = idx & 7, lane = (idx >> 3) & 63, rest = idx >> 9;
    int nt = rest & 7, kt = rest >> 3;
    int k = kt * 32 + (lane >> 4) * 8 + j;
    int n = nt * 16 + (lane & 15);
    float w = 0.f;
    if (k < K1 && n < N1) {
        int py = k / 28, px = k % 28;
        #pragma unroll
        for (int dy = 0; dy < 3; ++dy) {
            int oy = py - dy; if (oy < 0 || oy > 25) continue;
            #pragma unroll
            for (int dx = 0; dx < 3; ++dx) {
                int ox = px - dx; if (ox < 0 || ox > 25) continue;
                w += conv_w[dy * 3 + dx] * w1[(oy * 26 + ox) * N1 + n];
            }
        }
    }
    wp[(size_t)(kt * NTP + nt) * 512 + lane * 8 + j] = f2bf(w);
}

// ---------------------------------------------------------------------------
// Kernel 2: 256-thread blocks (4 waves), 64 rows/block, 1024 blocks.
// Per kt: B-tile (8 KB) staged to double-buffered LDS via global_load_lds.
// K-loop: counted s_waitcnt vmcnt(2) (x prefetch stays in flight across the
// barrier) with the SAFE barrier sandwich:
//   asm s_waitcnt vmcnt(2) lgkmcnt(0) ["memory"]   <- drain own staging+dsread
//   s_barrier                                       <- raw barrier (no fence!)
//   asm "" ["memory"]                               <- pin later reads BELOW
// (Round 6 lacked the post-barrier clobber: LLVM's s_barrier intrinsic is not
// a memory fence, so next-iter ds_reads hoisted above it -> cross-wave race.)
// ---------------------------------------------------------------------------
__global__ __launch_bounds__(256, 4) void fused_mfma(
    const float* __restrict__ x, const ushort* __restrict__ wp,
    const float* __restrict__ b1, const float* __restrict__ w2,
    const float* __restrict__ b2, const float* __restrict__ w3,
    const float* __restrict__ b3, float* __restrict__ out)
{
    __shared__ __attribute__((aligned(16))) ushort bsm[2][NTP * 512]; // 2x8KB
    __shared__ float w2t[10][112];   // transposed w2, padded cols 100..111 = 0
    __shared__ float w3s[100];
    __shared__ float b1s[100];
    __shared__ float b2s[10], b3s[10];

    const int tid  = threadIdx.x;
    const int lane = tid & 63;
    const int lo16 = lane & 15, hi4 = lane >> 4;
    const size_t row0 = (size_t)blockIdx.x * 64 + (tid >> 6) * 16;

    // zero w2t pad, then fill (barrier between to order the two writers)
    for (int e = tid; e < 10 * 112; e += 256) w2t[e / 112][e % 112] = 0.f;
    __syncthreads();
    for (int e = tid; e < 1000; e += 256) w2t[e % 10][e / 10] = w2[e];
    for (int e = tid; e < 100; e += 256) { w3s[e] = w3[e]; b1s[e] = b1[e]; }
    if (tid < 10) { b2s[tid] = b2[tid]; b3s[tid] = b3[tid]; }
    // Full drain: vmcnt ledger = 0 from here, so counted waits below are exact.
    __syncthreads();

    const float* xr = x + (row0 + lo16) * K1;

    f32x4 acc[NTT];
    #pragma unroll
    for (int n = 0; n < NTT; ++n) { f32x4 z = {0.f,0.f,0.f,0.f}; acc[n] = z; }

    // prologue: stage kt=0 B-tile (2 vmem), then x kt=0 (2 vmem)
    {
        const ushort* src = wp + tid * 8;
        gload_lds16(src,        &bsm[0][tid * 8]);
        gload_lds16(src + 2048, &bsm[0][tid * 8 + 2048]);
    }
    __builtin_amdgcn_sched_barrier(0);
    float4 cur0 = *reinterpret_cast<const float4*>(xr + hi4 * 8);
    float4 cur1 = *reinterpret_cast<const float4*>(xr + hi4 * 8 + 4);
    float4 nxt0 = cur0, nxt1 = cur1;
    asm volatile("s_waitcnt vmcnt(2)" ::: "memory");  // staging landed; x flies
    __builtin_amdgcn_s_barrier();
    asm volatile("" ::: "memory");   // post-barrier fence: no read hoists above

    for (int kt = 0; kt < KT; ++kt) {
        const int cur = kt & 1;
        if (kt < KT - 1) {
            // stage next B-tile FIRST (these 2 are what the barrier waits on)
            const ushort* src = wp + (size_t)(kt + 1) * (NTP * 512) + tid * 8;
            gload_lds16(src,        &bsm[cur ^ 1][tid * 8]);
            gload_lds16(src + 2048, &bsm[cur ^ 1][tid * 8 + 2048]);
            __builtin_amdgcn_sched_barrier(0);   // keep x loads YOUNGER
            int nb = (kt + 1) * 32 + hi4 * 8;
            if (nb > K1 - 8) nb = K1 - 8;   // pad region: B rows zero there
            nxt0 = *reinterpret_cast<const float4*>(xr + nb);
            nxt1 = *reinterpret_cast<const float4*>(xr + nb + 4);
        }
        bf16x8 ah = pack_bf16x8(cur0, cur1);
        const ushort* bb = &bsm[cur][lane * 8];
        #pragma unroll
        for (int nt = 0; nt < NTT; ++nt) {
            bf16x8 bh = *reinterpret_cast<const bf16x8*>(bb + nt * 512);
            acc[nt] = __builtin_amdgcn_mfma_f32_16x16x32_bf16(ah, bh,
                                                              acc[nt], 0,0,0);
        }
        // Counted wait: 2 youngest vmem (x prefetch) may stay in flight;
        // lgkmcnt(0) closes the ds_read WAR vs next-iter restage of bsm[cur].
        asm volatile("s_waitcnt vmcnt(2) lgkmcnt(0)" ::: "memory");
        __builtin_amdgcn_s_barrier();
        asm volatile("" ::: "memory");   // pin next-iter ds_reads below barrier
        cur0 = nxt0; cur1 = nxt1;
    }

    __syncthreads();   // full sync before LDS-read epilogue

    // ---- h1 = relu(acc + b1) in registers.
    // C layout (HW-verified): col = nt*16+lo16, row = hi4*4 + r
    float h1v[NTT][4];
    #pragma unroll
    for (int nt = 0; nt < NTT; ++nt) {
        int col = nt * 16 + lo16;
        bool valid = col < N1;
        float bb = valid ? b1s[valid ? col : 0] : 0.f;
        #pragma unroll
        for (int r = 0; r < 4; ++r)
            h1v[nt][r] = valid ? fmaxf(acc[nt][r] + bb, 0.f) : 0.f;
    }

    // ---- layers 2+3 fused: per j, partial over this lane's 7 cols,
    // xor-reduce across the 16-lane group, accumulate out on the fly.
    const int jj = lo16;                 // this lane's output column (if <10)
    float o[4] = {0.f, 0.f, 0.f, 0.f};
    #pragma unroll
    for (int j = 0; j < 10; ++j) {
        float pj[4] = {0.f, 0.f, 0.f, 0.f};
        #pragma unroll
        for (int nt = 0; nt < NTT; ++nt) {
            float wv = w2t[j][nt * 16 + lo16];   // padded: 0 beyond col 99
            #pragma unroll
            for (int r = 0; r < 4; ++r) pj[r] += h1v[nt][r] * wv;
        }
        #pragma unroll
        for (int mask = 8; mask >= 1; mask >>= 1)
            #pragma unroll
            for (int r = 0; r < 4; ++r)
                pj[r] += __shfl_xor(pj[r], mask, 16);
        float w3v = (jj < 10) ? w3s[j * 10 + jj] : 0.f;
        #pragma unroll
        for (int r = 0; r < 4; ++r) {
            float h2 = fmaxf(pj[r] + b2s[j], 0.f);
            o[r] += h2 * w3v;
        }
    }

    if (jj < 10) {
        #pragma unroll
        for (int r = 0; r < 4; ++r)
            out[(row0 + hi4 * 4 + r) * 10 + jj] = o[r] + b3s[jj];
    }
}

extern "C" void kernel_launch(void* const* d_in, const int* in_sizes, int n_in,
                              void* d_out, int out_size, void* d_ws, size_t ws_size,
                              hipStream_t stream) {
    const float* x     = (const float*)d_in[0];
    const float* convw = (const float*)d_in[1];
    const float* w1    = (const float*)d_in[2];
    const float* b1    = (const float*)d_in[3];
    const float* w2    = (const float*)d_in[4];
    const float* b2    = (const float*)d_in[5];
    const float* w3    = (const float*)d_in[6];
    const float* b3    = (const float*)d_in[7];
    float* out  = (float*)d_out;
    ushort* wp  = (ushort*)d_ws;   // 204,800 B packed W_eff (bf16 RNE, 8 nt/kt)

    build_wp<<<(KT * NTP * 512 + 255) / 256, 256, 0, stream>>>(w1, convw, wp);
    fused_mfma<<<65536 / 64, 256, 0, stream>>>(x, wp, b1, w2, b2, w3, b3, out);
}

// Round 9
// 51.461 us; speedup vs baseline: 1.0384x; 1.0384x over previous
//
#include <hip/hip_runtime.h>
#include <hip/hip_bf16.h>

#define K1 784
#define N1 100
#define KT 25    // k-tiles of 32 (K padded to 800; pad rows zero in packed W)
#define NTT 7    // live n-tiles of 16 (N=100 padded to 112)
#define NTP 8    // stored n-tiles per kt (padded to 8 for 2x global_load_lds)

typedef __attribute__((ext_vector_type(8))) short bf16x8;
typedef __attribute__((ext_vector_type(4))) float f32x4;

__device__ __forceinline__ ushort f2bf(float f) {
    union { float f; unsigned u; } v; v.f = f;
    unsigned u = v.u;
    return (ushort)((u + 0x7FFFu + ((u >> 16) & 1u)) >> 16);   // RNE
}

// 8x f32 -> 8x bf16 (RNE) via 4 packed converts
__device__ __forceinline__ bf16x8 pack_bf16x8(float4 a, float4 b) {
    union { unsigned u[4]; bf16x8 v; } r;
    asm("v_cvt_pk_bf16_f32 %0, %1, %2" : "=v"(r.u[0]) : "v"(a.x), "v"(a.y));
    asm("v_cvt_pk_bf16_f32 %0, %1, %2" : "=v"(r.u[1]) : "v"(a.z), "v"(a.w));
    asm("v_cvt_pk_bf16_f32 %0, %1, %2" : "=v"(r.u[2]) : "v"(b.x), "v"(b.y));
    asm("v_cvt_pk_bf16_f32 %0, %1, %2" : "=v"(r.u[3]) : "v"(b.z), "v"(b.w));
    return r.v;
}

// async 16B global -> LDS (direct, no VGPR round-trip)
__device__ __forceinline__ void gload_lds16(const void* g, void* l) {
    __builtin_amdgcn_global_load_lds(
        (const __attribute__((address_space(1))) void*)g,
        (__attribute__((address_space(3))) void*)l, 16, 0, 0);
}

// ---------------------------------------------------------------------------
// Kernel 1: fold conv into w1 -> W_eff[k][n] (bf16 RNE), stored in MFMA
// B-fragment order: wp[(kt*8+nt)*512 + lane*8 + j] with
//   k = kt*32 + (lane>>4)*8 + j, n = nt*16 + (lane&15).
// nt=7 / k>=784 / n>=100 are zero pad. Total 25*8*512*2B = 204,800 B.
// ---------------------------------------------------------------------------
__global__ void build_wp(const float* __restrict__ w1,
                         const float* __restrict__ conv_w,
                         ushort* __restrict__ wp) {
    int idx = blockIdx.x * blockDim.x + threadIdx.x;
    if (idx >= KT * NTP * 512) return;
    int j = idx & 7, lane = (idx >> 3) & 63, rest = idx >> 9;
    int nt = rest & 7, kt = rest >> 3;
    int k = kt * 32 + (lane >> 4) * 8 + j;
    int n = nt * 16 + (lane & 15);
    float w = 0.f;
    if (k < K1 && n < N1) {
        int py = k / 28, px = k % 28;
        #pragma unroll
        for (int dy = 0; dy < 3; ++dy) {
            int oy = py - dy; if (oy < 0 || oy > 25) continue;
            #pragma unroll
            for (int dx = 0; dx < 3; ++dx) {
                int ox = px - dx; if (ox < 0 || ox > 25) continue;
                w += conv_w[dy * 3 + dx] * w1[(oy * 26 + ox) * N1 + n];
            }
        }
    }
    wp[(size_t)(kt * NTP + nt) * 512 + lane * 8 + j] = f2bf(w);
}

// ---------------------------------------------------------------------------
// Kernel 2: 256-thread blocks (4 waves), 32 rows/wave (2 m-tiles), 128 rows
// per block, 512 blocks. Each ds_read_b128 B-frag feeds 2 MFMA.
// B triple-buffered in LDS (stage kt+2 during kt); x register pipeline depth
// 3 with FOUR slots (x(kt..kt+2) resident + x(kt+3) issued pre-consume;
// round 8 used 3 slots -> (kt+3)%3==kt%3 overwrote the tile being consumed).
// Exact vmcnt ledger (loop fully unrolled, all waits literal):
//   per iter kt: STAGE B(kt+2) (2) | LOADX x(kt+3) (4) | compute |
//   end wait = B(kt+1) staged: younger = L(kt+2)4 + S(kt+2)2 + L(kt+3)4 = 10
//   (kt=0: 14; kt=KT-3: 6; kt=KT-2: 0); then raw s_barrier + "" mem clobber.
// ---------------------------------------------------------------------------
__global__ __launch_bounds__(256, 2) void fused_mfma(
    const float* __restrict__ x, const ushort* __restrict__ wp,
    const float* __restrict__ b1, const float* __restrict__ w2,
    const float* __restrict__ b2, const float* __restrict__ w3,
    const float* __restrict__ b3, float* __restrict__ out)
{
    __shared__ __attribute__((aligned(16))) ushort bsm[3][NTP * 512]; // 3x8KB
    __shared__ float w2t[10][112];   // transposed w2, padded cols 100..111 = 0
    __shared__ float w3s[100];
    __shared__ float b1s[100];
    __shared__ float b2s[10], b3s[10];

    const int tid  = threadIdx.x;
    const int lane = tid & 63;
    const int lo16 = lane & 15, hi4 = lane >> 4;
    const int wid  = tid >> 6;
    const size_t rowbase = (size_t)blockIdx.x * 128 + wid * 32;

    // zero w2t pad, then fill (barrier between to order the two writers)
    for (int e = tid; e < 10 * 112; e += 256) w2t[e / 112][e % 112] = 0.f;
    __syncthreads();
    for (int e = tid; e < 1000; e += 256) w2t[e % 10][e / 10] = w2[e];
    for (int e = tid; e < 100; e += 256) { w3s[e] = w3[e]; b1s[e] = b1[e]; }
    if (tid < 10) { b2s[tid] = b2[tid]; b3s[tid] = b3[tid]; }
    // Full drain: vmcnt ledger = 0 from here, so counted waits below are exact.
    __syncthreads();

    const float* xr0 = x + (rowbase + lo16) * K1;        // m-tile 0
    const float* xr1 = xr0 + (size_t)16 * K1;            // m-tile 1

    f32x4 acc[2][NTT];
    #pragma unroll
    for (int m = 0; m < 2; ++m)
        #pragma unroll
        for (int n = 0; n < NTT; ++n) { f32x4 z = {0.f,0.f,0.f,0.f}; acc[m][n] = z; }

    float4 xs[4][4];   // [kt%4][m*2+half]; 4 slots: 3 resident + 1 in issue

#define STAGE(KTB)                                                            \
    { const ushort* src = wp + (size_t)(KTB) * (NTP * 512) + tid * 8;         \
      ushort* dst = &bsm[(KTB) % 3][tid * 8];                                 \
      gload_lds16(src, dst); gload_lds16(src + 2048, dst + 2048); }
#define LOADX(KTL, SLOT)                                                      \
    { int nb = (KTL) * 32 + hi4 * 8;                                          \
      if (nb > K1 - 8) nb = K1 - 8;  /* pad rows: B zero there */             \
      xs[SLOT][0] = *reinterpret_cast<const float4*>(xr0 + nb);               \
      xs[SLOT][1] = *reinterpret_cast<const float4*>(xr0 + nb + 4);           \
      xs[SLOT][2] = *reinterpret_cast<const float4*>(xr1 + nb);               \
      xs[SLOT][3] = *reinterpret_cast<const float4*>(xr1 + nb + 4); }

    // prologue: B0(2), x0(4), B1(2), x1(4), x2(4) = 16 outstanding.
    STAGE(0);
    __builtin_amdgcn_sched_barrier(0);
    LOADX(0, 0);
    __builtin_amdgcn_sched_barrier(0);
    STAGE(1);
    __builtin_amdgcn_sched_barrier(0);
    LOADX(1, 1);
    LOADX(2, 2);
    asm volatile("s_waitcnt vmcnt(14)" ::: "memory");   // B0 staged; rest flies
    __builtin_amdgcn_s_barrier();
    asm volatile("" ::: "memory");

    #pragma unroll
    for (int kt = 0; kt < KT; ++kt) {
        const int slot = kt % 4;      // x slot (4-deep)
        const int bslot = kt % 3;     // B LDS buffer (3-deep)
        if (kt <= KT - 3) {           // stage B(kt+2) into bsm[(kt+2)%3]
            STAGE(kt + 2);
            __builtin_amdgcn_sched_barrier(0);   // keep x loads YOUNGER than B
        }
        if (kt <= KT - 4) {           // issue x(kt+3) into the FREE 4th slot
            LOADX(kt + 3, (kt + 3) % 4);
        }
        bf16x8 ah0 = pack_bf16x8(xs[slot][0], xs[slot][1]);
        bf16x8 ah1 = pack_bf16x8(xs[slot][2], xs[slot][3]);
        const ushort* bb = &bsm[bslot][lane * 8];
        #pragma unroll
        for (int nt = 0; nt < NTT; ++nt) {
            bf16x8 bh = *reinterpret_cast<const bf16x8*>(bb + nt * 512);
            acc[0][nt] = __builtin_amdgcn_mfma_f32_16x16x32_bf16(ah0, bh,
                                                          acc[0][nt], 0,0,0);
            acc[1][nt] = __builtin_amdgcn_mfma_f32_16x16x32_bf16(ah1, bh,
                                                          acc[1][nt], 0,0,0);
        }
        if (kt < KT - 1) {
            // guarantee B(kt+1) staged; leave youngest x loads in flight.
            if (kt == 0)
                asm volatile("s_waitcnt vmcnt(14) lgkmcnt(0)" ::: "memory");
            else if (kt <= KT - 4)
                asm volatile("s_waitcnt vmcnt(10) lgkmcnt(0)" ::: "memory");
            else if (kt == KT - 3)
                asm volatile("s_waitcnt vmcnt(6) lgkmcnt(0)" ::: "memory");
            else
                asm volatile("s_waitcnt vmcnt(0) lgkmcnt(0)" ::: "memory");
            __builtin_amdgcn_s_barrier();
            asm volatile("" ::: "memory");   // pin next-iter reads below barrier
        }
    }
#undef STAGE
#undef LOADX

    __syncthreads();   // full sync before LDS-read epilogue

    // ---- h1 = relu(acc + b1) in registers.
    // C layout (HW-verified): col = nt*16+lo16, row = m*16 + hi4*4 + r
    float h1v[2][NTT][4];
    #pragma unroll
    for (int m = 0; m < 2; ++m)
        #pragma unroll
        for (int nt = 0; nt < NTT; ++nt) {
            int col = nt * 16 + lo16;
            bool valid = col < N1;
            float bb = valid ? b1s[valid ? col : 0] : 0.f;
            #pragma unroll
            for (int r = 0; r < 4; ++r)
                h1v[m][nt][r] = valid ? fmaxf(acc[m][nt][r] + bb, 0.f) : 0.f;
        }

    // ---- layers 2+3 fused per m-tile: per j, partial over this lane's 7
    // cols, xor-reduce across the 16-lane group, accumulate out on the fly.
    const int jj = lo16;                 // this lane's output column (if <10)
    #pragma unroll
    for (int m = 0; m < 2; ++m) {
        float o[4] = {0.f, 0.f, 0.f, 0.f};
        #pragma unroll
        for (int j = 0; j < 10; ++j) {
            float pj[4] = {0.f, 0.f, 0.f, 0.f};
            #pragma unroll
            for (int nt = 0; nt < NTT; ++nt) {
                float wv = w2t[j][nt * 16 + lo16];   // padded: 0 beyond col 99
                #pragma unroll
                for (int r = 0; r < 4; ++r) pj[r] += h1v[m][nt][r] * wv;
            }
            #pragma unroll
            for (int mask = 8; mask >= 1; mask >>= 1)
                #pragma unroll
                for (int r = 0; r < 4; ++r)
                    pj[r] += __shfl_xor(pj[r], mask, 16);
            float w3v = (jj < 10) ? w3s[j * 10 + jj] : 0.f;
            #pragma unroll
            for (int r = 0; r < 4; ++r) {
                float h2 = fmaxf(pj[r] + b2s[j], 0.f);
                o[r] += h2 * w3v;
            }
        }
        if (jj < 10) {
            #pragma unroll
            for (int r = 0; r < 4; ++r)
                out[(rowbase + m * 16 + hi4 * 4 + r) * 10 + jj] = o[r] + b3s[jj];
        }
    }
}

extern "C" void kernel_launch(void* const* d_in, const int* in_sizes, int n_in,
                              void* d_out, int out_size, void* d_ws, size_t ws_size,
                              hipStream_t stream) {
    const float* x     = (const float*)d_in[0];
    const float* convw = (const float*)d_in[1];
    const float* w1    = (const float*)d_in[2];
    const float* b1    = (const float*)d_in[3];
    const float* w2    = (const float*)d_in[4];
    const float* b2    = (const float*)d_in[5];
    const float* w3    = (const float*)d_in[6];
    const float* b3    = (const float*)d_in[7];
    float* out  = (float*)d_out;
    ushort* wp  = (ushort*)d_ws;   // 204,800 B packed W_eff (bf16 RNE, 8 nt/kt)

    build_wp<<<(KT * NTP * 512 + 255) / 256, 256, 0, stream>>>(w1, convw, wp);
    fused_mfma<<<65536 / 128, 256, 0, stream>>>(x, wp, b1, w2, b2, w3, b3, out);
}